// Round 15
// baseline (659.555 us; speedup 1.0000x reference)
//
#include <hip/hip_runtime.h>
#include <math.h>

#define Bq 8
#define Lq 65536
#define Hq 32
#define Nq 8
#define DEPq 4
#define LCq 64
#define NCq (Lq/LCq)     // 1024 chunks per b
#define GRPq 32
#define NGq  (NCq/GRPq)  // 32 groups
#define CHB 4            // chunks per k_main block
#define TPB (CHB*Hq)     // 128 threads

// ---------------- conditioning MLP + FiLM ----------------
__global__ void k_cond_film(const float* __restrict__ prm,
                            const float* __restrict__ W1, const float* __restrict__ b1,
                            const float* __restrict__ W2, const float* __restrict__ b2,
                            const float* __restrict__ W3, const float* __restrict__ b3,
                            const float* __restrict__ filmW, const float* __restrict__ filmB,
                            float* __restrict__ film /* [DEP][B][2H] */)
{
    __shared__ float cond[Bq][32];
    int tid = threadIdx.x, d = blockIdx.x;
    if (tid < Bq) {
        float p0 = prm[tid*2+0], p1 = prm[tid*2+1];
        float c1[16];
        #pragma unroll
        for (int i=0;i<16;i++){ float v = W1[i*2+0]*p0 + W1[i*2+1]*p1 + b1[i]; c1[i]=v>0.f?v:0.f; }
        float c2[32];
        #pragma unroll
        for (int i=0;i<32;i++){ float a=b2[i];
            #pragma unroll
            for(int j=0;j<16;j++) a = fmaf(W2[i*16+j], c1[j], a);
            c2[i]=a>0.f?a:0.f; }
        #pragma unroll
        for (int i=0;i<32;i++){ float a=b3[i];
            #pragma unroll
            for(int j=0;j<32;j++) a = fmaf(W3[i*32+j], c2[j], a);
            cond[tid][i]=a>0.f?a:0.f; }
    }
    __syncthreads();
    int b = tid>>6, k = tid&63;
    float a = filmB[d*2*Hq + k];
    #pragma unroll
    for (int j=0;j<32;j++) a = fmaf(cond[b][j], filmW[(d*2*Hq + k)*32 + j], a);
    film[(d*Bq + b)*2*Hq + k] = a;
}

// ---------------- S4D derived params ----------------
__global__ void k_s4params(const float* __restrict__ log_dt, const float* __restrict__ logAre,
                           const float* __restrict__ Aim_, const float* __restrict__ Cre_,
                           const float* __restrict__ Cim_,
                           float* __restrict__ pw, float* __restrict__ pc2,
                           float* __restrict__ pwL, float* __restrict__ pwG)
{
    int idx = threadIdx.x; // DEP*H*N = 1024
    int d = idx/(Hq*Nq); int h = (idx/Nq)%Hq;
    double dt = exp((double)log_dt[d*Hq+h]);
    double Are = -exp((double)logAre[idx]);
    double Aim = (double)Aim_[idx];
    double dar = dt*Are, dai = dt*Aim;
    double er = exp(dar);
    double wr = er*cos(dai), wi = er*sin(dai);
    double em1r = wr - 1.0, em1i = wi;
    double den = Are*Are + Aim*Aim;
    double qr = (em1r*Are + em1i*Aim)/den;
    double qi = (em1i*Are - em1r*Aim)/den;
    double Cr = (double)Cre_[idx], Ci = (double)Cim_[idx];
    double eL = exp(dar*(double)LCq);
    double eG = exp(dar*(double)(LCq*GRPq));
    pw [idx*2+0]=(float)wr;  pw [idx*2+1]=(float)wi;
    pc2[idx*2+0]=(float)(2.0*(Cr*qr - Ci*qi)); pc2[idx*2+1]=(float)(2.0*(Cr*qi + Ci*qr));
    pwL[idx*2+0]=(float)(eL*cos(dai*(double)LCq));        pwL[idx*2+1]=(float)(eL*sin(dai*(double)LCq));
    pwG[idx*2+0]=(float)(eG*cos(dai*(double)(LCq*GRPq))); pwG[idx*2+1]=(float)(eG*sin(dai*(double)(LCq*GRPq)));
}

// ---------------- premix for depth 0 ----------------
__global__ void k_premix(const float* __restrict__ linW, const float* __restrict__ linB,
                         const float* __restrict__ eW, const float* __restrict__ eb,
                         float* __restrict__ ab0)
{
    int g = threadIdx.x;  // 32
    float a = 0.f, be = linB[g];
    #pragma unroll
    for (int h=0;h<Hq;h++){ a = fmaf(linW[g*Hq+h], eW[h], a); be = fmaf(linW[g*Hq+h], eb[h], be); }
    ab0[g] = a; ab0[32+g] = be;
}

// ---------------- k_first: u0 = relu(x*al+be), chunk-local scan_0 -> sloc ----------------
__global__ __launch_bounds__(256) void k_first(
    const float* __restrict__ x, const float* __restrict__ ab0,
    const float* __restrict__ pw, float* __restrict__ sloc)
{
    __shared__ float xs[LCq];
    int tid = threadIdx.x;
    int cg = blockIdx.x; int b = cg >> 10, c = cg & (NCq-1);
    if (tid < LCq) xs[tid] = x[(size_t)b*Lq + (size_t)c*LCq + tid];
    __syncthreads();
    int ch = tid >> 3, m = tid & 7;
    float wr = pw[(ch*Nq+m)*2], wi = pw[(ch*Nq+m)*2+1];
    float al = ab0[ch], be = ab0[32+ch];
    float sr = 0.f, si = 0.f;
    #pragma unroll 4
    for (int j=0;j<LCq;j++){
        float u = fmaf(xs[j], al, be); u = u>0.f?u:0.f;
        float nr = fmaf(wr, sr, fmaf(-wi, si, u));
        float ni = fmaf(wr, si, wi*sr);
        sr=nr; si=ni;
    }
    size_t sb = ((size_t)(b*NCq + c)*Hq + ch)*16;
    sloc[sb+m] = sr; sloc[sb+8+m] = si;
}

// ---------------- pass2: two-level prefix over chunks, block per (b,h) ----------------
__global__ __launch_bounds__(256) void k_pass2(const float* __restrict__ sloc,
    const float* __restrict__ pwL, const float* __restrict__ pwG, float* __restrict__ sini)
{
    __shared__ float aux[NGq*Nq*2];
    int bid = blockIdx.x; int b = bid >> 5, h = bid & 31;
    int tid = threadIdx.x;
    int n = tid & 7, g2 = tid >> 3;
    float wLr = pwL[(h*Nq+n)*2], wLi = pwL[(h*Nq+n)*2+1];
    float sr=0.f, si=0.f;
    for (int k=0;k<GRPq;k++){
        size_t off = ((size_t)(b*NCq + g2*GRPq+k)*Hq + h)*16;
        float lr = sloc[off+n], li = sloc[off+8+n];
        float nr = fmaf(wLr,sr, fmaf(-wLi,si, lr));
        float ni = fmaf(wLr,si, fmaf( wLi,sr, li));
        sr=nr; si=ni;
    }
    aux[(g2*8+n)*2+0]=sr; aux[(g2*8+n)*2+1]=si;
    __syncthreads();
    if (tid < 8) {
        float wGr = pwG[(h*Nq+tid)*2], wGi = pwG[(h*Nq+tid)*2+1];
        float pr=0.f, pi=0.f;
        for (int g=0; g<NGq; g++){
            float er_ = aux[(g*8+tid)*2+0], ei_ = aux[(g*8+tid)*2+1];
            aux[(g*8+tid)*2+0]=pr; aux[(g*8+tid)*2+1]=pi;
            float nr = fmaf(wGr,pr, fmaf(-wGi,pi, er_));
            float ni = fmaf(wGr,pi, fmaf( wGi,pr, ei_));
            pr=nr; pi=ni;
        }
    }
    __syncthreads();
    sr = aux[(g2*8+n)*2+0]; si = aux[(g2*8+n)*2+1];
    for (int k=0;k<GRPq;k++){
        size_t off = ((size_t)(b*NCq + g2*GRPq+k)*Hq + h)*16;
        float lr = sloc[off+n], li = sloc[off+8+n];
        sini[off+n] = sr; sini[off+8+n] = si;
        float nr = fmaf(wLr,sr, fmaf(-wLi,si, lr));
        float ni = fmaf(wLr,si, fmaf( wLi,sr, li));
        sr=nr; si=ni;
    }
}

// ---------------- fused per-depth kernel, MODE 0=first 1=mid 2=last ----------------
// thread = (chunk cc, channel ch); NO LDS. Rows via global/L1 broadcast.
// Fused P1+P2: per step {mix_d -> u, scan step, film, relu, residual -> hbuf}
// barrier; P3: mix_{d+1} (rows re-read from hbuf) + zero-seed local scan -> sloc
template<int MODE>
__global__ __launch_bounds__(TPB) void k_mainT(
    const float* __restrict__ x, float* __restrict__ hbuf,
    const float* __restrict__ eW, const float* __restrict__ eb,
    const float* __restrict__ ab0,
    const float* __restrict__ linW_d, const float* __restrict__ linB_d,
    const float* __restrict__ linW_n, const float* __restrict__ linB_n,
    const float* __restrict__ pw_d, const float* __restrict__ pc2_d,
    const float* __restrict__ pw_n,
    const float* __restrict__ sini, float* __restrict__ sloc,
    const float* __restrict__ Dskip, const float* __restrict__ film,
    const float* __restrict__ resw,
    const float* __restrict__ cW, const float* __restrict__ cb,
    float* __restrict__ out)
{
    const int tid = threadIdx.x;
    const int cc = tid >> 5, ch = tid & 31;
    const int cg0 = blockIdx.x * CHB;
    const int b = cg0 >> 10;
    const int c = (cg0 & (NCq-1)) + cc;
    const size_t rec0 = ((size_t)b*Lq + (size_t)c*LCq)*Hq;
    const size_t xo0  = (size_t)b*Lq + (size_t)c*LCq;

    float W[Hq];
    if (MODE != 0) {
        #pragma unroll
        for (int k=0;k<8;k++) ((float4*)W)[k] = ((const float4*)(linW_d + ch*Hq))[k];
    }
    float lb = (MODE!=0) ? linB_d[ch] : 0.f;
    float al = 0.f, be = 0.f;
    if (MODE == 0){ al = ab0[ch]; be = ab0[32+ch]; }

    float wr[Nq],wi[Nq],cr[Nq],ci[Nq],sr[Nq],si[Nq];
    #pragma unroll
    for (int n=0;n<Nq;n++){
        wr[n]=pw_d[(ch*Nq+n)*2];  wi[n]=pw_d[(ch*Nq+n)*2+1];
        cr[n]=pc2_d[(ch*Nq+n)*2]; ci[n]=pc2_d[(ch*Nq+n)*2+1];
    }
    const size_t sb = ((size_t)(b*NCq + c)*Hq + ch)*16;
    #pragma unroll
    for (int n=0;n<Nq;n++){ sr[n]=sini[sb+n]; si[n]=sini[sb+8+n]; }
    float D  = Dskip[ch];
    float gf = film[b*2*Hq + ch], bf = film[b*2*Hq + Hq + ch];
    float rw = resw[ch];
    float eWc = eW[ch], ebc = eb[ch];
    float cw  = (MODE==2) ? cW[ch] : 0.f;
    float cb0 = (MODE==2) ? cb[0]  : 0.f;

    // ---- fused P1+P2 ----
    #pragma unroll 2
    for (int j=0;j<LCq;j++){
        float u, ho;
        if (MODE == 0) {
            float xv = x[xo0 + j];
            u = fmaf(xv, al, be); u = u>0.f?u:0.f;
            ho = fmaf(xv, eWc, ebc);
        } else {
            const float4* r4 = (const float4*)(hbuf + rec0 + (size_t)j*Hq);
            float a0=lb, a1=0.f, a2=0.f, a3=0.f;
            #pragma unroll
            for (int k=0;k<8;k++){
                float4 v = r4[k];
                a0 = fmaf(W[4*k+0], v.x, a0);
                a1 = fmaf(W[4*k+1], v.y, a1);
                a2 = fmaf(W[4*k+2], v.z, a2);
                a3 = fmaf(W[4*k+3], v.w, a3);
            }
            u = (a0+a1)+(a2+a3);
            u = u>0.f?u:0.f;
            ho = hbuf[rec0 + (size_t)j*Hq + ch];   // scalar coalesced (no reg-indexing)
        }
        float y = D*u;
        #pragma unroll
        for (int n=0;n<Nq;n++){
            float nr = fmaf(wr[n],sr[n], fmaf(-wi[n],si[n], u));
            float ni = fmaf(wr[n],si[n], wi[n]*sr[n]);
            sr[n]=nr; si[n]=ni;
            y = fmaf(cr[n],nr,y);
            y = fmaf(-ci[n],ni,y);
        }
        y = fmaf(y,gf,bf);
        y = y>0.f?y:0.f;
        float hn = fmaf(rw, ho, y);
        if (MODE == 2) {
            float val = cw*hn;
            val += __shfl_xor(val, 1);
            val += __shfl_xor(val, 2);
            val += __shfl_xor(val, 4);
            val += __shfl_xor(val, 8);
            val += __shfl_xor(val, 16);
            if (ch == 0) out[xo0 + j] = x[xo0 + j]*tanhf(val + cb0);
        } else {
            hbuf[rec0 + (size_t)j*Hq + ch] = hn;   // lanes 0..31 consecutive -> coalesced
        }
    }
    if (MODE == 2) return;

    __syncthreads();   // drain vmcnt: h_new visible block-wide

    // ---- P3: mix_{d+1} + zero-seeded local scan -> sloc ----
    {
        #pragma unroll
        for (int k=0;k<8;k++) ((float4*)W)[k] = ((const float4*)(linW_n + ch*Hq))[k];
        float lbn = linB_n[ch];
        float vr[Nq],vi[Nq],tr_[Nq],ti_[Nq];
        #pragma unroll
        for (int n=0;n<Nq;n++){
            vr[n]=pw_n[(ch*Nq+n)*2]; vi[n]=pw_n[(ch*Nq+n)*2+1];
            tr_[n]=0.f; ti_[n]=0.f;
        }
        #pragma unroll 2
        for (int j=0;j<LCq;j++){
            const float4* r4 = (const float4*)(hbuf + rec0 + (size_t)j*Hq);
            float a0=lbn, a1=0.f, a2=0.f, a3=0.f;
            #pragma unroll
            for (int k=0;k<8;k++){
                float4 v = r4[k];
                a0 = fmaf(W[4*k+0], v.x, a0);
                a1 = fmaf(W[4*k+1], v.y, a1);
                a2 = fmaf(W[4*k+2], v.z, a2);
                a3 = fmaf(W[4*k+3], v.w, a3);
            }
            float u = (a0+a1)+(a2+a3);
            u = u>0.f?u:0.f;
            #pragma unroll
            for (int n=0;n<Nq;n++){
                float nr = fmaf(vr[n],tr_[n], fmaf(-vi[n],ti_[n], u));
                float ni = fmaf(vr[n],ti_[n], vi[n]*tr_[n]);
                tr_[n]=nr; ti_[n]=ni;
            }
        }
        #pragma unroll
        for (int n=0;n<Nq;n++){ sloc[sb+n]=tr_[n]; sloc[sb+8+n]=ti_[n]; }
    }
}

// ---------------- diagnostic flag ----------------
__global__ void k_flag(float* __restrict__ out, int code) { out[0] = (float)code; }

extern "C" void kernel_launch(void* const* d_in, const int* in_sizes, int n_in,
                              void* d_out, int out_size, void* d_ws, size_t ws_size,
                              hipStream_t stream)
{
    const float* x    = (const float*)d_in[0];
    const float* prm  = (const float*)d_in[1];
    const float* W1   = (const float*)d_in[2];  const float* b1 = (const float*)d_in[3];
    const float* W2   = (const float*)d_in[4];  const float* b2 = (const float*)d_in[5];
    const float* W3   = (const float*)d_in[6];  const float* b3 = (const float*)d_in[7];
    const float* eW   = (const float*)d_in[8];  const float* eb = (const float*)d_in[9];
    const float* linW = (const float*)d_in[10]; const float* linB = (const float*)d_in[11];
    const float* log_dt = (const float*)d_in[12]; const float* logAre = (const float*)d_in[13];
    const float* Aim  = (const float*)d_in[14]; const float* Cre = (const float*)d_in[15];
    const float* Cim  = (const float*)d_in[16]; const float* Dskip = (const float*)d_in[17];
    const float* filmW= (const float*)d_in[18]; const float* filmB = (const float*)d_in[19];
    const float* resw = (const float*)d_in[20]; const float* cW = (const float*)d_in[21];
    const float* cb   = (const float*)d_in[22];

    float* sloc = (float*)d_ws;                                    // 4194304 f
    float* sini = sloc + (size_t)Bq*NCq*Hq*16;                     // 4194304 f
    float* pw   = sini + (size_t)Bq*NCq*Hq*16;                     // 2048 f
    float* pc2  = pw  + DEPq*Hq*Nq*2;                              // 2048 f
    float* pwL  = pc2 + DEPq*Hq*Nq*2;                              // 2048 f
    float* pwG  = pwL + DEPq*Hq*Nq*2;                              // 2048 f
    float* film = pwG + DEPq*Hq*Nq*2;                              // 2048 f
    float* ab0  = film + DEPq*Bq*2*Hq;                             // 64 f
    float* hbuf = ab0 + 64;                                        // 16777216 f
    float* out  = (float*)d_out;
    size_t ws_needed = (char*)(hbuf + (size_t)Bq*Lq*Hq) - (char*)d_ws;

    hipLaunchKernelGGL(k_cond_film, dim3(DEPq), dim3(512), 0, stream,
                       prm,W1,b1,W2,b2,W3,b3,filmW,filmB,film);
    hipLaunchKernelGGL(k_s4params, dim3(1), dim3(DEPq*Hq*Nq), 0, stream,
                       log_dt,logAre,Aim,Cre,Cim,pw,pc2,pwL,pwG);
    hipLaunchKernelGGL(k_premix, dim3(1), dim3(Hq), 0, stream, linW, linB, eW, eb, ab0);
    hipLaunchKernelGGL(k_first, dim3(Bq*NCq), dim3(256), 0, stream, x, ab0, pw, sloc);

    const int main_grid = Bq*NCq/CHB;   // 2048
    for (int d=0; d<DEPq; d++){
        hipLaunchKernelGGL(k_pass2, dim3(Bq*Hq), dim3(256), 0, stream,
                           sloc, pwL + d*Hq*Nq*2, pwG + d*Hq*Nq*2, sini);
        int dn = (d < DEPq-1) ? d+1 : d;
        if (d == 0) {
            hipLaunchKernelGGL((k_mainT<0>), dim3(main_grid), dim3(TPB), 0, stream,
                x, hbuf, eW, eb, ab0,
                linW + d*Hq*Hq, linB + d*Hq, linW + dn*Hq*Hq, linB + dn*Hq,
                pw + d*Hq*Nq*2, pc2 + d*Hq*Nq*2, pw + dn*Hq*Nq*2,
                sini, sloc, Dskip + d*Hq, film + d*Bq*2*Hq, resw + d*Hq,
                cW, cb, out);
        } else if (d < DEPq-1) {
            hipLaunchKernelGGL((k_mainT<1>), dim3(main_grid), dim3(TPB), 0, stream,
                x, hbuf, eW, eb, ab0,
                linW + d*Hq*Hq, linB + d*Hq, linW + dn*Hq*Hq, linB + dn*Hq,
                pw + d*Hq*Nq*2, pc2 + d*Hq*Nq*2, pw + dn*Hq*Nq*2,
                sini, sloc, Dskip + d*Hq, film + d*Bq*2*Hq, resw + d*Hq,
                cW, cb, out);
        } else {
            hipLaunchKernelGGL((k_mainT<2>), dim3(main_grid), dim3(TPB), 0, stream,
                x, hbuf, eW, eb, ab0,
                linW + d*Hq*Hq, linB + d*Hq, linW + dn*Hq*Hq, linB + dn*Hq,
                pw + d*Hq*Nq*2, pc2 + d*Hq*Nq*2, pw + dn*Hq*Nq*2,
                sini, sloc, Dskip + d*Hq, film + d*Bq*2*Hq, resw + d*Hq,
                cW, cb, out);
        }
    }

    static const int expected[23] = {
        Bq*Lq, Bq*2, 32, 16, 512, 32, 1024, 32, Hq, Hq,
        DEPq*Hq*Hq, DEPq*Hq, DEPq*Hq, DEPq*Hq*Nq, DEPq*Hq*Nq, DEPq*Hq*Nq, DEPq*Hq*Nq,
        DEPq*Hq, DEPq*2*Hq*32, DEPq*2*Hq, DEPq*Hq, Hq, 1
    };
    int code = 0;
    if (n_in != 23) code = 99;
    else { for (int i = 0; i < 23; i++) if (in_sizes[i] != expected[i]) { code = 100 + i; break; } }
    if (!code && ws_size < ws_needed) code = 200;
    if (code) hipLaunchKernelGGL(k_flag, dim3(1), dim3(1), 0, stream, out, code);
}

// Round 16
// 493.511 us; speedup vs baseline: 1.3365x; 1.3365x over previous
//
#include <hip/hip_runtime.h>
#include <math.h>

#define Bq 8
#define Lq 65536
#define Hq 32
#define Nq 8
#define DEPq 4
#define LCq 64
#define NCq (Lq/LCq)     // 1024 chunks per b
#define GRPq 32
#define NGq  (NCq/GRPq)  // 32 groups

// ---------------- conditioning MLP + FiLM ----------------
__global__ void k_cond_film(const float* __restrict__ prm,
                            const float* __restrict__ W1, const float* __restrict__ b1,
                            const float* __restrict__ W2, const float* __restrict__ b2,
                            const float* __restrict__ W3, const float* __restrict__ b3,
                            const float* __restrict__ filmW, const float* __restrict__ filmB,
                            float* __restrict__ film /* [DEP][B][2H] */)
{
    __shared__ float cond[Bq][32];
    int tid = threadIdx.x, d = blockIdx.x;
    if (tid < Bq) {
        float p0 = prm[tid*2+0], p1 = prm[tid*2+1];
        float c1[16];
        #pragma unroll
        for (int i=0;i<16;i++){ float v = W1[i*2+0]*p0 + W1[i*2+1]*p1 + b1[i]; c1[i]=v>0.f?v:0.f; }
        float c2[32];
        #pragma unroll
        for (int i=0;i<32;i++){ float a=b2[i];
            #pragma unroll
            for(int j=0;j<16;j++) a = fmaf(W2[i*16+j], c1[j], a);
            c2[i]=a>0.f?a:0.f; }
        #pragma unroll
        for (int i=0;i<32;i++){ float a=b3[i];
            #pragma unroll
            for(int j=0;j<32;j++) a = fmaf(W3[i*32+j], c2[j], a);
            cond[tid][i]=a>0.f?a:0.f; }
    }
    __syncthreads();
    int b = tid>>6, k = tid&63;
    float a = filmB[d*2*Hq + k];
    #pragma unroll
    for (int j=0;j<32;j++) a = fmaf(cond[b][j], filmW[(d*2*Hq + k)*32 + j], a);
    film[(d*Bq + b)*2*Hq + k] = a;
}

// ---------------- S4D derived params ----------------
__global__ void k_s4params(const float* __restrict__ log_dt, const float* __restrict__ logAre,
                           const float* __restrict__ Aim_, const float* __restrict__ Cre_,
                           const float* __restrict__ Cim_,
                           float* __restrict__ pw, float* __restrict__ pc2,
                           float* __restrict__ pwL, float* __restrict__ pwG)
{
    int idx = threadIdx.x; // DEP*H*N = 1024
    int d = idx/(Hq*Nq); int h = (idx/Nq)%Hq;
    double dt = exp((double)log_dt[d*Hq+h]);
    double Are = -exp((double)logAre[idx]);
    double Aim = (double)Aim_[idx];
    double dar = dt*Are, dai = dt*Aim;
    double er = exp(dar);
    double wr = er*cos(dai), wi = er*sin(dai);
    double em1r = wr - 1.0, em1i = wi;
    double den = Are*Are + Aim*Aim;
    double qr = (em1r*Are + em1i*Aim)/den;
    double qi = (em1i*Are - em1r*Aim)/den;
    double Cr = (double)Cre_[idx], Ci = (double)Cim_[idx];
    double eL = exp(dar*(double)LCq);
    double eG = exp(dar*(double)(LCq*GRPq));
    pw [idx*2+0]=(float)wr;  pw [idx*2+1]=(float)wi;
    pc2[idx*2+0]=(float)(2.0*(Cr*qr - Ci*qi)); pc2[idx*2+1]=(float)(2.0*(Cr*qi + Ci*qr));
    pwL[idx*2+0]=(float)(eL*cos(dai*(double)LCq));        pwL[idx*2+1]=(float)(eL*sin(dai*(double)LCq));
    pwG[idx*2+0]=(float)(eG*cos(dai*(double)(LCq*GRPq))); pwG[idx*2+1]=(float)(eG*sin(dai*(double)(LCq*GRPq)));
}

// ---------------- premix for depth 0 ----------------
__global__ void k_premix(const float* __restrict__ linW, const float* __restrict__ linB,
                         const float* __restrict__ eW, const float* __restrict__ eb,
                         float* __restrict__ ab0)
{
    int g = threadIdx.x;  // 32
    float a = 0.f, be = linB[g];
    #pragma unroll
    for (int h=0;h<Hq;h++){ a = fmaf(linW[g*Hq+h], eW[h], a); be = fmaf(linW[g*Hq+h], eb[h], be); }
    ab0[g] = a; ab0[32+g] = be;
}

// ---------------- k_first: u0 = relu(x*al+be), chunk-local scan_0 -> sloc ----------------
__global__ __launch_bounds__(256) void k_first(
    const float* __restrict__ x, const float* __restrict__ ab0,
    const float* __restrict__ pw, float* __restrict__ sloc)
{
    __shared__ float xs[LCq];
    int tid = threadIdx.x;
    int cg = blockIdx.x; int b = cg >> 10, c = cg & (NCq-1);
    if (tid < LCq) xs[tid] = x[(size_t)b*Lq + (size_t)c*LCq + tid];
    __syncthreads();
    int ch = tid >> 3, m = tid & 7;
    float wr = pw[(ch*Nq+m)*2], wi = pw[(ch*Nq+m)*2+1];
    float al = ab0[ch], be = ab0[32+ch];
    float sr = 0.f, si = 0.f;
    #pragma unroll 4
    for (int j=0;j<LCq;j++){
        float u = fmaf(xs[j], al, be); u = u>0.f?u:0.f;
        float nr = fmaf(wr, sr, fmaf(-wi, si, u));
        float ni = fmaf(wr, si, wi*sr);
        sr=nr; si=ni;
    }
    size_t sb = ((size_t)(b*NCq + c)*Hq + ch)*16;
    sloc[sb+m] = sr; sloc[sb+8+m] = si;
}

// ---------------- pass2: two-level prefix over chunks, block per (b,h) ----------------
__global__ __launch_bounds__(256) void k_pass2(const float* __restrict__ sloc,
    const float* __restrict__ pwL, const float* __restrict__ pwG, float* __restrict__ sini)
{
    __shared__ float aux[NGq*Nq*2];
    int bid = blockIdx.x; int b = bid >> 5, h = bid & 31;
    int tid = threadIdx.x;
    int n = tid & 7, g2 = tid >> 3;
    float wLr = pwL[(h*Nq+n)*2], wLi = pwL[(h*Nq+n)*2+1];
    float sr=0.f, si=0.f;
    for (int k=0;k<GRPq;k++){
        size_t off = ((size_t)(b*NCq + g2*GRPq+k)*Hq + h)*16;
        float lr = sloc[off+n], li = sloc[off+8+n];
        float nr = fmaf(wLr,sr, fmaf(-wLi,si, lr));
        float ni = fmaf(wLr,si, fmaf( wLi,sr, li));
        sr=nr; si=ni;
    }
    aux[(g2*8+n)*2+0]=sr; aux[(g2*8+n)*2+1]=si;
    __syncthreads();
    if (tid < 8) {
        float wGr = pwG[(h*Nq+tid)*2], wGi = pwG[(h*Nq+tid)*2+1];
        float pr=0.f, pi=0.f;
        for (int g=0; g<NGq; g++){
            float er_ = aux[(g*8+tid)*2+0], ei_ = aux[(g*8+tid)*2+1];
            aux[(g*8+tid)*2+0]=pr; aux[(g*8+tid)*2+1]=pi;
            float nr = fmaf(wGr,pr, fmaf(-wGi,pi, er_));
            float ni = fmaf(wGr,pi, fmaf( wGi,pr, ei_));
            pr=nr; pi=ni;
        }
    }
    __syncthreads();
    sr = aux[(g2*8+n)*2+0]; si = aux[(g2*8+n)*2+1];
    for (int k=0;k<GRPq;k++){
        size_t off = ((size_t)(b*NCq + g2*GRPq+k)*Hq + h)*16;
        float lr = sloc[off+n], li = sloc[off+8+n];
        sini[off+n] = sr; sini[off+8+n] = si;
        float nr = fmaf(wLr,sr, fmaf(-wLi,si, lr));
        float ni = fmaf(wLr,si, fmaf( wLi,sr, li));
        sr=nr; si=ni;
    }
}

// ---------------- fused per-depth kernel, MODE 0=first 1=mid 2=last ----------------
// block = 1 wave = 64 threads = 2 chunks x 32 channels. LDS = two 32-float rows
// per chunk (512 B). Loop1: {scalar h read -> row -> mix_d -> scan -> film ->
// residual -> scalar h write}. Loop2: {h_new reread (L1) -> row -> mix_{d+1} ->
// local scan -> sloc}. Wave-lockstep orders row write before row reads.
template<int MODE>
__global__ __launch_bounds__(64) void k_mainT(
    const float* __restrict__ x, float* __restrict__ hbuf,
    const float* __restrict__ eW, const float* __restrict__ eb,
    const float* __restrict__ ab0,
    const float* __restrict__ linW_d, const float* __restrict__ linB_d,
    const float* __restrict__ linW_n, const float* __restrict__ linB_n,
    const float* __restrict__ pw_d, const float* __restrict__ pc2_d,
    const float* __restrict__ pw_n,
    const float* __restrict__ sini, float* __restrict__ sloc,
    const float* __restrict__ Dskip, const float* __restrict__ film,
    const float* __restrict__ resw,
    const float* __restrict__ cW, const float* __restrict__ cb,
    float* __restrict__ out)
{
    __shared__ float rowA[2][Hq];
    __shared__ float rowB[2][Hq];
    const int tid = threadIdx.x;
    const int cc = tid >> 5, ch = tid & 31;
    const int cg = blockIdx.x*2 + cc;
    const int b = cg >> 10;
    const int c = cg & (NCq-1);
    const size_t rec0 = ((size_t)b*Lq + (size_t)c*LCq)*Hq;
    const size_t xo0  = (size_t)b*Lq + (size_t)c*LCq;

    // ---- Loop 1: mix_d + seeded scan + film + relu + residual ----
    {
        float W[Hq];
        float lb=0.f, al=0.f, be=0.f;
        if (MODE == 0){ al = ab0[ch]; be = ab0[32+ch]; }
        else {
            #pragma unroll
            for (int k=0;k<8;k++) ((float4*)W)[k] = ((const float4*)(linW_d + ch*Hq))[k];
            lb = linB_d[ch];
        }
        float wr[Nq],wi[Nq],cr[Nq],ci[Nq],sr[Nq],si[Nq];
        #pragma unroll
        for (int n=0;n<Nq;n++){
            wr[n]=pw_d[(ch*Nq+n)*2];  wi[n]=pw_d[(ch*Nq+n)*2+1];
            cr[n]=pc2_d[(ch*Nq+n)*2]; ci[n]=pc2_d[(ch*Nq+n)*2+1];
        }
        const size_t sb = ((size_t)(b*NCq + c)*Hq + ch)*16;
        #pragma unroll
        for (int n=0;n<Nq;n++){ sr[n]=sini[sb+n]; si[n]=sini[sb+8+n]; }
        float D  = Dskip[ch];
        float gf = film[b*2*Hq + ch], bf = film[b*2*Hq + Hq + ch];
        float rw = resw[ch];
        float eWc = eW[ch], ebc = eb[ch];
        float cw  = (MODE==2) ? cW[ch] : 0.f;
        float cb0 = (MODE==2) ? cb[0]  : 0.f;

        #pragma unroll 2
        for (int j=0;j<LCq;j++){
            float u, ho;
            if (MODE == 0) {
                float xv = x[xo0 + j];
                u = fmaf(xv, al, be); u = u>0.f?u:0.f;
                ho = fmaf(xv, eWc, ebc);
            } else {
                ho = hbuf[rec0 + (size_t)j*Hq + ch];
                rowA[cc][ch] = ho;
                const float4* r4 = (const float4*)(&rowA[cc][0]);
                float a0=lb, a1=0.f, a2=0.f, a3=0.f;
                #pragma unroll
                for (int k=0;k<8;k++){
                    float4 v = r4[k];
                    a0 = fmaf(W[4*k+0], v.x, a0);
                    a1 = fmaf(W[4*k+1], v.y, a1);
                    a2 = fmaf(W[4*k+2], v.z, a2);
                    a3 = fmaf(W[4*k+3], v.w, a3);
                }
                u = (a0+a1)+(a2+a3);
                u = u>0.f?u:0.f;
            }
            float y = D*u;
            #pragma unroll
            for (int n=0;n<Nq;n++){
                float nr = fmaf(wr[n],sr[n], fmaf(-wi[n],si[n], u));
                float ni = fmaf(wr[n],si[n], wi[n]*sr[n]);
                sr[n]=nr; si[n]=ni;
                y = fmaf(cr[n],nr,y);
                y = fmaf(-ci[n],ni,y);
            }
            y = fmaf(y,gf,bf);
            y = y>0.f?y:0.f;
            float hn = fmaf(rw, ho, y);
            if (MODE == 2) {
                float val = cw*hn;
                val += __shfl_xor(val, 1);
                val += __shfl_xor(val, 2);
                val += __shfl_xor(val, 4);
                val += __shfl_xor(val, 8);
                val += __shfl_xor(val, 16);
                if (ch == 0) out[xo0 + j] = x[xo0 + j]*tanhf(val + cb0);
            } else {
                hbuf[rec0 + (size_t)j*Hq + ch] = hn;
            }
        }
    }
    if (MODE == 2) return;

    // ---- Loop 2: mix_{d+1} + zero-seeded local scan -> sloc ----
    {
        float W[Hq];
        #pragma unroll
        for (int k=0;k<8;k++) ((float4*)W)[k] = ((const float4*)(linW_n + ch*Hq))[k];
        float lbn = linB_n[ch];
        float vr[Nq],vi[Nq],tr_[Nq],ti_[Nq];
        #pragma unroll
        for (int n=0;n<Nq;n++){
            vr[n]=pw_n[(ch*Nq+n)*2]; vi[n]=pw_n[(ch*Nq+n)*2+1];
            tr_[n]=0.f; ti_[n]=0.f;
        }
        #pragma unroll 2
        for (int j=0;j<LCq;j++){
            float hn = hbuf[rec0 + (size_t)j*Hq + ch];   // L1-hot (just written)
            rowB[cc][ch] = hn;
            const float4* r4 = (const float4*)(&rowB[cc][0]);
            float a0=lbn, a1=0.f, a2=0.f, a3=0.f;
            #pragma unroll
            for (int k=0;k<8;k++){
                float4 v = r4[k];
                a0 = fmaf(W[4*k+0], v.x, a0);
                a1 = fmaf(W[4*k+1], v.y, a1);
                a2 = fmaf(W[4*k+2], v.z, a2);
                a3 = fmaf(W[4*k+3], v.w, a3);
            }
            float u = (a0+a1)+(a2+a3);
            u = u>0.f?u:0.f;
            #pragma unroll
            for (int n=0;n<Nq;n++){
                float nr = fmaf(vr[n],tr_[n], fmaf(-vi[n],ti_[n], u));
                float ni = fmaf(vr[n],ti_[n], vi[n]*tr_[n]);
                tr_[n]=nr; ti_[n]=ni;
            }
        }
        const size_t sb = ((size_t)(b*NCq + c)*Hq + ch)*16;
        #pragma unroll
        for (int n=0;n<Nq;n++){ sloc[sb+n]=tr_[n]; sloc[sb+8+n]=ti_[n]; }
    }
}

// ---------------- diagnostic flag ----------------
__global__ void k_flag(float* __restrict__ out, int code) { out[0] = (float)code; }

extern "C" void kernel_launch(void* const* d_in, const int* in_sizes, int n_in,
                              void* d_out, int out_size, void* d_ws, size_t ws_size,
                              hipStream_t stream)
{
    const float* x    = (const float*)d_in[0];
    const float* prm  = (const float*)d_in[1];
    const float* W1   = (const float*)d_in[2];  const float* b1 = (const float*)d_in[3];
    const float* W2   = (const float*)d_in[4];  const float* b2 = (const float*)d_in[5];
    const float* W3   = (const float*)d_in[6];  const float* b3 = (const float*)d_in[7];
    const float* eW   = (const float*)d_in[8];  const float* eb = (const float*)d_in[9];
    const float* linW = (const float*)d_in[10]; const float* linB = (const float*)d_in[11];
    const float* log_dt = (const float*)d_in[12]; const float* logAre = (const float*)d_in[13];
    const float* Aim  = (const float*)d_in[14]; const float* Cre = (const float*)d_in[15];
    const float* Cim  = (const float*)d_in[16]; const float* Dskip = (const float*)d_in[17];
    const float* filmW= (const float*)d_in[18]; const float* filmB = (const float*)d_in[19];
    const float* resw = (const float*)d_in[20]; const float* cW = (const float*)d_in[21];
    const float* cb   = (const float*)d_in[22];

    float* sloc = (float*)d_ws;                                    // 4194304 f
    float* sini = sloc + (size_t)Bq*NCq*Hq*16;                     // 4194304 f
    float* pw   = sini + (size_t)Bq*NCq*Hq*16;                     // 2048 f
    float* pc2  = pw  + DEPq*Hq*Nq*2;                              // 2048 f
    float* pwL  = pc2 + DEPq*Hq*Nq*2;                              // 2048 f
    float* pwG  = pwL + DEPq*Hq*Nq*2;                              // 2048 f
    float* film = pwG + DEPq*Hq*Nq*2;                              // 2048 f
    float* ab0  = film + DEPq*Bq*2*Hq;                             // 64 f
    float* hbuf = ab0 + 64;                                        // 16777216 f
    float* out  = (float*)d_out;
    size_t ws_needed = (char*)(hbuf + (size_t)Bq*Lq*Hq) - (char*)d_ws;

    hipLaunchKernelGGL(k_cond_film, dim3(DEPq), dim3(512), 0, stream,
                       prm,W1,b1,W2,b2,W3,b3,filmW,filmB,film);
    hipLaunchKernelGGL(k_s4params, dim3(1), dim3(DEPq*Hq*Nq), 0, stream,
                       log_dt,logAre,Aim,Cre,Cim,pw,pc2,pwL,pwG);
    hipLaunchKernelGGL(k_premix, dim3(1), dim3(Hq), 0, stream, linW, linB, eW, eb, ab0);
    hipLaunchKernelGGL(k_first, dim3(Bq*NCq), dim3(256), 0, stream, x, ab0, pw, sloc);

    const int main_grid = Bq*NCq/2;   // 4096 blocks x 64 threads
    for (int d=0; d<DEPq; d++){
        hipLaunchKernelGGL(k_pass2, dim3(Bq*Hq), dim3(256), 0, stream,
                           sloc, pwL + d*Hq*Nq*2, pwG + d*Hq*Nq*2, sini);
        int dn = (d < DEPq-1) ? d+1 : d;
        if (d == 0) {
            hipLaunchKernelGGL((k_mainT<0>), dim3(main_grid), dim3(64), 0, stream,
                x, hbuf, eW, eb, ab0,
                linW + d*Hq*Hq, linB + d*Hq, linW + dn*Hq*Hq, linB + dn*Hq,
                pw + d*Hq*Nq*2, pc2 + d*Hq*Nq*2, pw + dn*Hq*Nq*2,
                sini, sloc, Dskip + d*Hq, film + d*Bq*2*Hq, resw + d*Hq,
                cW, cb, out);
        } else if (d < DEPq-1) {
            hipLaunchKernelGGL((k_mainT<1>), dim3(main_grid), dim3(64), 0, stream,
                x, hbuf, eW, eb, ab0,
                linW + d*Hq*Hq, linB + d*Hq, linW + dn*Hq*Hq, linB + dn*Hq,
                pw + d*Hq*Nq*2, pc2 + d*Hq*Nq*2, pw + dn*Hq*Nq*2,
                sini, sloc, Dskip + d*Hq, film + d*Bq*2*Hq, resw + d*Hq,
                cW, cb, out);
        } else {
            hipLaunchKernelGGL((k_mainT<2>), dim3(main_grid), dim3(64), 0, stream,
                x, hbuf, eW, eb, ab0,
                linW + d*Hq*Hq, linB + d*Hq, linW + dn*Hq*Hq, linB + dn*Hq,
                pw + d*Hq*Nq*2, pc2 + d*Hq*Nq*2, pw + dn*Hq*Nq*2,
                sini, sloc, Dskip + d*Hq, film + d*Bq*2*Hq, resw + d*Hq,
                cW, cb, out);
        }
    }

    static const int expected[23] = {
        Bq*Lq, Bq*2, 32, 16, 512, 32, 1024, 32, Hq, Hq,
        DEPq*Hq*Hq, DEPq*Hq, DEPq*Hq, DEPq*Hq*Nq, DEPq*Hq*Nq, DEPq*Hq*Nq, DEPq*Hq*Nq,
        DEPq*Hq, DEPq*2*Hq*32, DEPq*2*Hq, DEPq*Hq, Hq, 1
    };
    int code = 0;
    if (n_in != 23) code = 99;
    else { for (int i = 0; i < 23; i++) if (in_sizes[i] != expected[i]) { code = 100 + i; break; } }
    if (!code && ws_size < ws_needed) code = 200;
    if (code) hipLaunchKernelGGL(k_flag, dim3(1), dim3(1), 0, stream, out, code);
}